// Round 17
// baseline (1892.521 us; speedup 1.0000x reference)
//
#include <hip/hip_runtime.h>
#include <float.h>

#pragma clang fp contract(off)

#define B_ 16
#define N_ 4096
#define M_ 1024
#define K_ 32
#define FEAT_ 64
#define H_ 128
#define GEO_IN_ 160
#define GEO_MID_ 130
#define FEAT_IN_ 2048

typedef unsigned short u16t;
typedef float f32x2 __attribute__((ext_vector_type(2)));

// ---- wave64 reductions in the VALU pipe (DPP), identity-preserving ----
#define DPP_STEP_MAX(ctrl) \
  t=(unsigned)__builtin_amdgcn_update_dpp((int)v,(int)v,(ctrl),0xf,0xf,false); \
  v=(t>v)?t:v;
#define DPP_STEP_MIN(ctrl) \
  t=(unsigned)__builtin_amdgcn_update_dpp((int)v,(int)v,(ctrl),0xf,0xf,false); \
  v=(t<v)?t:v;

__device__ __forceinline__ unsigned wave_max_u32(unsigned v){
  unsigned t;
  DPP_STEP_MAX(0x111) DPP_STEP_MAX(0x112) DPP_STEP_MAX(0x114) DPP_STEP_MAX(0x118)
  DPP_STEP_MAX(0x142) DPP_STEP_MAX(0x143)
  return (unsigned)__builtin_amdgcn_readlane((int)v,63);
}
__device__ __forceinline__ unsigned wave_min_u32(unsigned v){
  unsigned t;
  DPP_STEP_MIN(0x111) DPP_STEP_MIN(0x112) DPP_STEP_MIN(0x114) DPP_STEP_MIN(0x118)
  DPP_STEP_MIN(0x142) DPP_STEP_MIN(0x143)
  return (unsigned)__builtin_amdgcn_readlane((int)v,63);
}

// ---------------------------------------------------------------- FPS v5
// ONE WAVE per batch (64 thr), 64 pts/thread as 32 packed f32x2 pairs.
// Rationale (r16 counters): 4-wave version spends ~1300 of 1530 cyc/step on
// cross-wave selection (2x DPP + publish + __syncthreads + LDS round-trip +
// merge). Single wave: selection completes in-wave (proven 2-phase DPP),
// winner coords via ONE wave-uniform pl[sbi] LDS broadcast, ZERO barriers in
// the main loop. Issue concentrates on 1 SIMD (~960 cyc/step) but total
// ~1200 < 1530. All pieces HW-proven: packed body bits (r2/r4), 2-phase DPP
// (r10-r16), LDS table + uniform broadcast read (r12), static vector-array
// indices only (r7 scratch rule). Pair p: x-half j=p (idx tid+64p), y-half
// j=p+32 (idx tid+64p+2048) => all x-half idx < y-half; strict > in-loop
// keeps smallest p; ywin strict > prefers x-half == sequential tie-break.
__global__ __launch_bounds__(64) void fps_kernel(
    const float* __restrict__ xyz, float* __restrict__ outc)
{
  const int b = blockIdx.x, tid = threadIdx.x;   // tid 0..63, one wave
  const float* xb = xyz + (size_t)b * (N_*3);
  __shared__ __align__(16) float4 pl[N_];        // 64 KB staged xyz
  __shared__ float clist[M_][3];                 // 12 KB

  for (int i=tid; i<N_; i+=64)
    pl[i] = make_float4(xb[i*3], xb[i*3+1], xb[i*3+2], 0.f);
  float lx=xb[0], ly=xb[1], lz=xb[2];
  if (tid==0){ clist[0][0]=lx; clist[0][1]=ly; clist[0][2]=lz; }
  __syncthreads();                               // staging fence (once)

  f32x2 PX[32], PY[32], PZ[32], DD[32];
#pragma unroll
  for (int p=0;p<32;p++){                        // static indices only
    float4 a = pl[tid + 64*p];                   // j=p      (x-half)
    float4 c = pl[tid + 64*p + 2048];            // j=p+32   (y-half)
    PX[p] = (f32x2){a.x, c.x};
    PY[p] = (f32x2){a.y, c.y};
    PZ[p] = (f32x2){a.z, c.z};
    DD[p] = (f32x2){FLT_MAX, FLT_MAX};
  }

  for (int t=1;t<M_;t++){
    f32x2 lxv=(f32x2){lx,lx}, lyv=(f32x2){ly,ly}, lzv=(f32x2){lz,lz};
    f32x2 bd2=(f32x2){-FLT_MAX,-FLT_MAX};
    int bpx=0, bpy=0;
#pragma unroll
    for (int p=0;p<32;p++){                      // verbatim r2 packed body
      f32x2 dx=PX[p]-lxv, dy=PY[p]-lyv, dz=PZ[p]-lzv;
      f32x2 m1=dx*dx, m2=dy*dy, m3=dz*dz;
      f32x2 s=(m1+m2)+m3;                        // same op order as scalar _rn
      f32x2 nd=__builtin_elementwise_min(DD[p], s);
      DD[p]=nd;
      if (nd.x>bd2.x){ bd2.x=nd.x; bpx=p; }      // strict > keeps smallest p
      if (nd.y>bd2.y){ bd2.y=nd.y; bpy=p; }
    }
    bool ywin = (bd2.y > bd2.x);                 // tie -> x-half (smaller idx)
    float bd = ywin ? bd2.y : bd2.x;
    int   bi = tid + 64*(ywin ? bpy+32 : bpx);
    unsigned db=__float_as_uint(bd);             // bd>=0 => bit order monotone
    unsigned smax=wave_max_u32(db);
    unsigned cand=(db==smax)?(unsigned)bi:0x7FFFFFFFu;
    unsigned sbi=wave_min_u32(cand);             // wave-uniform winner index
    float4 cw = pl[sbi];                         // uniform LDS broadcast read
    lx=cw.x; ly=cw.y; lz=cw.z;
    if (tid==0){ clist[t][0]=lx; clist[t][1]=ly; clist[t][2]=lz; }
  }
  __syncthreads();                               // clist fence before writeout
  for (int e=tid; e<M_; e+=64){
    size_t cb=((size_t)b*M_+(size_t)e)*3;
    outc[cb]=clist[e][0]; outc[cb+1]=clist[e][1]; outc[cb+2]=clist[e][2];
  }
}

// ---------------------------------------------------------------- KNN
// PROVEN wave-parallel-refill version (r11).
__global__ __launch_bounds__(256) void knn_kernel(
    const float* __restrict__ xyz, const float* __restrict__ outc,
    u16t* __restrict__ gidx16)
{
  const int w = blockIdx.x*4 + (threadIdx.x>>6);
  const int lane = threadIdx.x & 63;
  const int b = w >> 10;
  const float* xb = xyz + (size_t)b*(N_*3);
  float cx=outc[(size_t)w*3], cy=outc[(size_t)w*3+1], cz=outc[(size_t)w*3+2];
  float c2=__fadd_rn(__fadd_rn(__fmul_rn(cx,cx),__fmul_rn(cy,cy)),__fmul_rn(cz,cz));

  float lv=FLT_MAX; int lj=0;
#pragma unroll
  for (int j=0;j<64;j++){
    int i = lane + 64*j;
    float xx=xb[i*3], xy=xb[i*3+1], xz=xb[i*3+2];
    float x2=__fadd_rn(__fadd_rn(__fmul_rn(xx,xx),__fmul_rn(xy,xy)),__fmul_rn(xz,xz));
    float dt=__fadd_rn(__fadd_rn(__fmul_rn(cx,xx),__fmul_rn(cy,xy)),__fmul_rn(cz,xz));
    float d=__fsub_rn(__fadd_rn(c2,x2),__fmul_rn(2.f,dt));
    if (d<lv){ lv=d; lj=j; }               // strict <: smallest j attaining min
  }
  unsigned long long cons = 0ull;          // my consumed slots
  const int wb = w*K_;
  for (int k=0;k<K_;k++){
    unsigned u=__float_as_uint(lv);
    u = (u&0x80000000u) ? ~u : (u|0x80000000u);   // order-preserving transform
    unsigned smin=wave_min_u32(u);
    unsigned cand=(u==smin)?(unsigned)(lane+64*lj):0xFFFFFFFFu;
    unsigned widx=wave_min_u32(cand);
    if (lane==0) gidx16[wb+k]=(u16t)widx;
    int owner=(int)(widx & 63u);
    int slot =(int)(widx >> 6);
    if (lane==owner) cons |= (1ull<<(unsigned)slot);
    if (k==K_-1) break;                    // nothing consumes the last refill
    unsigned clo=(unsigned)__builtin_amdgcn_readlane((int)(unsigned)cons, owner);
    unsigned chi=(unsigned)__builtin_amdgcn_readlane((int)(unsigned)(cons>>32), owner);
    unsigned long long ocons=((unsigned long long)chi<<32)|(unsigned long long)clo;
    int ip = owner + 64*lane;
    float xx=xb[ip*3], xy=xb[ip*3+1], xz=xb[ip*3+2];
    float x2=__fadd_rn(__fadd_rn(__fmul_rn(xx,xx),__fmul_rn(xy,xy)),__fmul_rn(xz,xz));
    float dt=__fadd_rn(__fadd_rn(__fmul_rn(cx,xx),__fmul_rn(cy,xy)),__fmul_rn(cz,xz));
    float d=__fsub_rn(__fadd_rn(c2,x2),__fmul_rn(2.f,dt));
    unsigned uj=__float_as_uint(d);
    uj=(uj&0x80000000u)?~uj:(uj|0x80000000u);
    if ((ocons>>(unsigned)lane)&1ull) uj=0xFFFFFFFFu;   // exclude consumed
    unsigned smin2=wave_min_u32(uj);
    unsigned cs=(uj==smin2)?(unsigned)lane:64u;
    unsigned sslot=wave_min_u32(cs);                    // smallest slot at min
    float dnew=__uint_as_float((unsigned)__builtin_amdgcn_readlane(__float_as_int(d),(int)sslot));
    if (lane==owner){ lv=dnew; lj=(int)sslot; }
  }
}

// ---------------------------------------------------------------- GEO+FEAT fused launch
// PROVEN (r16). Blocks 0-511 = geo body; 512-767 = feat body (256 thr).
__global__ __launch_bounds__(256) void geofeat_kernel(
    const float* __restrict__ xyz, const float* __restrict__ outc,
    const u16t* __restrict__ gidx16,
    const float* __restrict__ gW1, const float* __restrict__ gWout,
    const float* __restrict__ feats,
    const float* __restrict__ fW1, const float* __restrict__ fb1,
    const float* __restrict__ fWout, const float* __restrict__ fbout,
    float* __restrict__ xout)
{
  __shared__ float smem[160*33 + 64*128 + 32];   // 54.0 KB
  const int t=threadIdx.x;
  if (blockIdx.x < 512){
    // ------------------------------ GEO body (proven, verbatim)
    float (*Es)[33]  = (float(*)[33])smem;
    float (*Hs)[33]  = (float(*)[33])smem;
    float (*Ws)[128] = (float(*)[128])(smem + 160*33);
    float* ssv = smem + 160*33 + 64*128;

    const int g0=blockIdx.x*32;
    for (int p=t; p<1024; p+=256){
      int g=p>>5, kk=p&31;
      int gg=g0+g, b=gg>>10;
      int idx=gidx16[gg*K_+kk];
      const float* pt = xyz + ((size_t)b*N_+(size_t)idx)*3;
      const float* cc = outc + (size_t)gg*3;
      float dx=__fsub_rn(pt[0],cc[0]);
      float dy=__fsub_rn(pt[1],cc[1]);
      float dz=__fsub_rn(pt[2],cc[2]);
      float sq=__fadd_rn(__fadd_rn(__fmul_rn(dx,dx),__fmul_rn(dy,dy)),__fmul_rn(dz,dz));
      int r=5*kk;
      Es[r][g]=dx; Es[r+1][g]=dy; Es[r+2][g]=dz;
      Es[r+3][g]=-1.f; Es[r+4][g]=__fmul_rn(-0.5f,sq);
    }
    const int gsub=t>>4, hsub=t&15, h0=hsub*8;
    const int hw=t>>1;
    float acc[2][8];
#pragma unroll
    for (int a=0;a<2;a++)
#pragma unroll
      for (int j=0;j<8;j++) acc[a][j]=0.f;
    __syncthreads();

    for (int c=0;c<3;c++){
      int i0=c*64;
      if (c<2){
        int fw0=(t&1)*32;
        const float* wr = gW1 + (size_t)hw*GEO_IN_ + i0 + fw0;
        float4 wv[8];
#pragma unroll
        for (int e=0;e<8;e++) wv[e]=((const float4*)wr)[e];
#pragma unroll
        for (int e=0;e<8;e++){
          Ws[fw0+4*e+0][hw]=wv[e].x;
          Ws[fw0+4*e+1][hw]=wv[e].y;
          Ws[fw0+4*e+2][hw]=wv[e].z;
          Ws[fw0+4*e+3][hw]=wv[e].w;
        }
      } else {
        int fw0=(t&1)*16;
        const float* wr = gW1 + (size_t)hw*GEO_IN_ + 128 + fw0;
        float4 wv[4];
#pragma unroll
        for (int e=0;e<4;e++) wv[e]=((const float4*)wr)[e];
#pragma unroll
        for (int e=0;e<4;e++){
          Ws[fw0+4*e+0][hw]=wv[e].x;
          Ws[fw0+4*e+1][hw]=wv[e].y;
          Ws[fw0+4*e+2][hw]=wv[e].z;
          Ws[fw0+4*e+3][hw]=wv[e].w;
        }
      }
      __syncthreads();
      int len=(c==2)?32:64;
      for (int k2=0;k2<len;k2++){
        float x0=Es[i0+k2][2*gsub], x1=Es[i0+k2][2*gsub+1];
        const float* wp=&Ws[k2][h0];
        float4 wa=*(const float4*)wp;
        float4 wb=*(const float4*)(wp+4);
        acc[0][0]=__builtin_fmaf(x0,wa.x,acc[0][0]);
        acc[0][1]=__builtin_fmaf(x0,wa.y,acc[0][1]);
        acc[0][2]=__builtin_fmaf(x0,wa.z,acc[0][2]);
        acc[0][3]=__builtin_fmaf(x0,wa.w,acc[0][3]);
        acc[0][4]=__builtin_fmaf(x0,wb.x,acc[0][4]);
        acc[0][5]=__builtin_fmaf(x0,wb.y,acc[0][5]);
        acc[0][6]=__builtin_fmaf(x0,wb.z,acc[0][6]);
        acc[0][7]=__builtin_fmaf(x0,wb.w,acc[0][7]);
        acc[1][0]=__builtin_fmaf(x1,wa.x,acc[1][0]);
        acc[1][1]=__builtin_fmaf(x1,wa.y,acc[1][1]);
        acc[1][2]=__builtin_fmaf(x1,wa.z,acc[1][2]);
        acc[1][3]=__builtin_fmaf(x1,wa.w,acc[1][3]);
        acc[1][4]=__builtin_fmaf(x1,wb.x,acc[1][4]);
        acc[1][5]=__builtin_fmaf(x1,wb.y,acc[1][5]);
        acc[1][6]=__builtin_fmaf(x1,wb.z,acc[1][6]);
        acc[1][7]=__builtin_fmaf(x1,wb.w,acc[1][7]);
      }
      __syncthreads();
    }
#pragma unroll
    for (int a=0;a<2;a++)
#pragma unroll
      for (int j=0;j<8;j++)
        Hs[h0+j][2*gsub+a]=acc[a][j];
    __syncthreads();
    if (t<32){
      float ss=0.f;
      for (int h=0;h<H_;h++){ float v=Hs[h][t]; ss=__builtin_fmaf(v,v,ss); }
      ssv[t]=__fmul_rn(-0.5f,ss);
    }
#pragma unroll
    for (int a=0;a<2;a++)
#pragma unroll
      for (int j=0;j<8;j++) acc[a][j]=0.f;
    for (int c=0;c<2;c++){
      int i0=c*64;
      int fw0=(t&1)*32;
      const float* wr = gWout + (size_t)hw*GEO_MID_ + i0 + fw0;
      float2 wv2[16];
#pragma unroll
      for (int e=0;e<16;e++) wv2[e]=((const float2*)wr)[e];
      __syncthreads();
#pragma unroll
      for (int e=0;e<16;e++){
        Ws[fw0+2*e+0][hw]=wv2[e].x;
        Ws[fw0+2*e+1][hw]=wv2[e].y;
      }
      __syncthreads();
      for (int k2=0;k2<64;k2++){
        float x0=Hs[i0+k2][2*gsub], x1=Hs[i0+k2][2*gsub+1];
        const float* wp=&Ws[k2][h0];
        float4 wa=*(const float4*)wp;
        float4 wb=*(const float4*)(wp+4);
        acc[0][0]=__builtin_fmaf(x0,wa.x,acc[0][0]);
        acc[0][1]=__builtin_fmaf(x0,wa.y,acc[0][1]);
        acc[0][2]=__builtin_fmaf(x0,wa.z,acc[0][2]);
        acc[0][3]=__builtin_fmaf(x0,wa.w,acc[0][3]);
        acc[0][4]=__builtin_fmaf(x0,wb.x,acc[0][4]);
        acc[0][5]=__builtin_fmaf(x0,wb.y,acc[0][5]);
        acc[0][6]=__builtin_fmaf(x0,wb.z,acc[0][6]);
        acc[0][7]=__builtin_fmaf(x0,wb.w,acc[0][7]);
        acc[1][0]=__builtin_fmaf(x1,wa.x,acc[1][0]);
        acc[1][1]=__builtin_fmaf(x1,wa.y,acc[1][1]);
        acc[1][2]=__builtin_fmaf(x1,wa.z,acc[1][2]);
        acc[1][3]=__builtin_fmaf(x1,wa.w,acc[1][3]);
        acc[1][4]=__builtin_fmaf(x1,wb.x,acc[1][4]);
        acc[1][5]=__builtin_fmaf(x1,wb.y,acc[1][5]);
        acc[1][6]=__builtin_fmaf(x1,wb.z,acc[1][6]);
        acc[1][7]=__builtin_fmaf(x1,wb.w,acc[1][7]);
      }
    }
#pragma unroll
    for (int j=0;j<8;j++){
      int o=h0+j;
      float2 we=*(const float2*)(gWout + (size_t)o*GEO_MID_ + 128);
#pragma unroll
      for (int a=0;a<2;a++){
        float v=acc[a][j];
        v=__builtin_fmaf(-1.f, we.x, v);
        v=__builtin_fmaf(ssv[2*gsub+a], we.y, v);
        xout[(size_t)(g0+2*gsub+a)*256 + o]=v;
      }
    }
  } else {
    // ------------------------------ FEAT body (proven r12 256-thr, verbatim)
    float (*Xs)[68]  = (float(*)[68])smem;             // [64][68]
    float (*Ws)[128] = (float(*)[128])(smem + 64*68);  // [64][128]
    float (*Hs)[68]  = (float(*)[68])smem;             // [128][68] alias
    float (*WoS)[128]= (float(*)[128])(smem + 128*68); // [32][128]
    const int g0=(blockIdx.x-512)*64;
    const int gsub=t>>4;
    const int h0=(t&15)*8;
    const int glx=t>>2, fq=(t&3)*16;
    const int hw=t>>1, fw0=(t&1)*32;
    const int fw1=(t&1)*16;
    const int gld=g0+glx, bld=gld>>10;
    float acc[4][8];
#pragma unroll
    for (int a=0;a<4;a++)
#pragma unroll
      for (int j=0;j<8;j++) acc[a][j]=0.f;

    for (int kk=0;kk<K_;kk++){
      int nidx=gidx16[gld*K_+kk];
      const float* fr=feats + ((size_t)bld*N_+(size_t)nidx)*FEAT_ + fq;
      float4 p[4];
#pragma unroll
      for (int e=0;e<4;e++) p[e]=((const float4*)fr)[e];
      const float* wr=fW1 + (size_t)hw*FEAT_IN_ + kk*64 + fw0;
      float4 wv[8];
#pragma unroll
      for (int e=0;e<8;e++) wv[e]=((const float4*)wr)[e];
#pragma unroll
      for (int e=0;e<4;e++){
        Xs[fq+4*e+0][glx]=p[e].x;
        Xs[fq+4*e+1][glx]=p[e].y;
        Xs[fq+4*e+2][glx]=p[e].z;
        Xs[fq+4*e+3][glx]=p[e].w;
      }
#pragma unroll
      for (int e=0;e<8;e++){
        Ws[fw0+4*e+0][hw]=wv[e].x;
        Ws[fw0+4*e+1][hw]=wv[e].y;
        Ws[fw0+4*e+2][hw]=wv[e].z;
        Ws[fw0+4*e+3][hw]=wv[e].w;
      }
      __syncthreads();
#pragma unroll 4
      for (int k2=0;k2<64;k2++){
        float4 xv=*(const float4*)&Xs[k2][4*gsub];
        const float* wp=&Ws[k2][h0];
        float4 wa=*(const float4*)wp;
        float4 wb=*(const float4*)(wp+4);
        float xr[4]={xv.x,xv.y,xv.z,xv.w};
        float wf[8]={wa.x,wa.y,wa.z,wa.w,wb.x,wb.y,wb.z,wb.w};
#pragma unroll
        for (int a=0;a<4;a++)
#pragma unroll
          for (int j=0;j<8;j++)
            acc[a][j]=__builtin_fmaf(xr[a],wf[j],acc[a][j]);
      }
      __syncthreads();
    }
#pragma unroll
    for (int j=0;j<8;j++){
      float bv=fb1[h0+j];
#pragma unroll
      for (int a=0;a<4;a++)
        Hs[h0+j][4*gsub+a]=fmaxf(__fadd_rn(acc[a][j],bv),0.f);
    }
    float ac2[4][8];
#pragma unroll
    for (int a=0;a<4;a++)
#pragma unroll
      for (int j=0;j<8;j++) ac2[a][j]=0.f;
    for (int c=0;c<4;c++){
      const float* wr2=fWout + (size_t)hw*H_ + c*32 + fw1;
      float4 w2[4];
#pragma unroll
      for (int e=0;e<4;e++) w2[e]=((const float4*)wr2)[e];
      __syncthreads();
#pragma unroll
      for (int e=0;e<4;e++){
        WoS[fw1+4*e+0][hw]=w2[e].x;
        WoS[fw1+4*e+1][hw]=w2[e].y;
        WoS[fw1+4*e+2][hw]=w2[e].z;
        WoS[fw1+4*e+3][hw]=w2[e].w;
      }
      __syncthreads();
#pragma unroll 4
      for (int k2=0;k2<32;k2++){
        float4 xv=*(const float4*)&Hs[c*32+k2][4*gsub];
        const float* wp=&WoS[k2][h0];
        float4 wa=*(const float4*)wp;
        float4 wb=*(const float4*)(wp+4);
        float xr[4]={xv.x,xv.y,xv.z,xv.w};
        float wf[8]={wa.x,wa.y,wa.z,wa.w,wb.x,wb.y,wb.z,wb.w};
#pragma unroll
        for (int a=0;a<4;a++)
#pragma unroll
          for (int j=0;j<8;j++)
            ac2[a][j]=__builtin_fmaf(xr[a],wf[j],ac2[a][j]);
      }
    }
#pragma unroll
    for (int j=0;j<8;j++){
      float bv=fbout[h0+j];
#pragma unroll
      for (int a=0;a<4;a++)
        xout[(size_t)(g0+4*gsub+a)*256+128+h0+j]=__fadd_rn(ac2[a][j],bv);
    }
  }
}

// ----------------------------------------------------------------
extern "C" void kernel_launch(void* const* d_in, const int* in_sizes, int n_in,
                              void* d_out, int out_size, void* d_ws, size_t ws_size,
                              hipStream_t stream) {
  const float* xyz  =(const float*)d_in[0];
  const float* feats=(const float*)d_in[1];
  const float* gW1  =(const float*)d_in[2];
  const float* gWout=(const float*)d_in[3];
  const float* fW1  =(const float*)d_in[4];
  const float* fb1  =(const float*)d_in[5];
  const float* fWout=(const float*)d_in[6];
  const float* fbout=(const float*)d_in[7];
  float* out=(float*)d_out;

  u16t* gidx16=(u16t*)d_ws;          // 1 MB
  float* xout = out + (size_t)B_*M_*3;

  fps_kernel    <<<dim3(B_),        dim3(64),  0, stream>>>(xyz, out);
  knn_kernel    <<<dim3((B_*M_)/4), dim3(256), 0, stream>>>(xyz, out, gidx16);
  geofeat_kernel<<<dim3(768),       dim3(256), 0, stream>>>(
      xyz, out, gidx16, gW1, gWout, feats, fW1, fb1, fWout, fbout, xout);
}

// Round 19
// 1075.803 us; speedup vs baseline: 1.7592x; 1.7592x over previous
//
#include <hip/hip_runtime.h>
#include <float.h>

#pragma clang fp contract(off)

#define B_ 16
#define N_ 4096
#define M_ 1024
#define K_ 32
#define FEAT_ 64
#define H_ 128
#define GEO_IN_ 160
#define GEO_MID_ 130
#define FEAT_IN_ 2048

typedef unsigned short u16t;
typedef float f32x2 __attribute__((ext_vector_type(2)));

// ---- wave64 reductions in the VALU pipe (DPP), identity-preserving ----
#define DPP_STEP_MAX(ctrl) \
  t=(unsigned)__builtin_amdgcn_update_dpp((int)v,(int)v,(ctrl),0xf,0xf,false); \
  v=(t>v)?t:v;
#define DPP_STEP_MIN(ctrl) \
  t=(unsigned)__builtin_amdgcn_update_dpp((int)v,(int)v,(ctrl),0xf,0xf,false); \
  v=(t<v)?t:v;

__device__ __forceinline__ unsigned wave_max_u32(unsigned v){
  unsigned t;
  DPP_STEP_MAX(0x111) DPP_STEP_MAX(0x112) DPP_STEP_MAX(0x114) DPP_STEP_MAX(0x118)
  DPP_STEP_MAX(0x142) DPP_STEP_MAX(0x143)
  return (unsigned)__builtin_amdgcn_readlane((int)v,63);
}
__device__ __forceinline__ unsigned wave_min_u32(unsigned v){
  unsigned t;
  DPP_STEP_MIN(0x111) DPP_STEP_MIN(0x112) DPP_STEP_MIN(0x114) DPP_STEP_MIN(0x118)
  DPP_STEP_MIN(0x142) DPP_STEP_MIN(0x143)
  return (unsigned)__builtin_amdgcn_readlane((int)v,63);
}

// ---------------------------------------------------------------- FPS v4
// PROVEN (r12/r14/r16: 653us). FROZEN: three structural alternatives all
// regressed (r6 2waves/SIMD 784; r10 tree+ballot 872; r17 1-wave 64pts/thr
// 1457 -- VGPR demand 256+ > file, compiler spilled to scratch, VGPR=136).
// 256 thr / 4 waves, 16 pts/thread as 8 packed f32x2 pairs (in-register),
// LDS xyz table + speculative own-candidate read, always-2-phase DPP,
// key+coords parallel publish/merge.
__global__ __launch_bounds__(256) void fps_kernel(
    const float* __restrict__ xyz, float* __restrict__ outc)
{
  const int b = blockIdx.x, tid = threadIdx.x;
  const int wv = tid >> 6;
  const float* xb = xyz + (size_t)b * (N_*3);
  __shared__ __align__(16) float4 pl[N_];   // 64 KB staged xyz
  __shared__ unsigned long long kkey[2][4];
  __shared__ __align__(16) float4 kxyz[2][4];
  __shared__ float clist[M_][3];            // 12 KB

  for (int i=tid; i<N_; i+=256)
    pl[i] = make_float4(xb[i*3], xb[i*3+1], xb[i*3+2], 0.f);
  float lx=xb[0], ly=xb[1], lz=xb[2];
  if (tid==0){ clist[0][0]=lx; clist[0][1]=ly; clist[0][2]=lz; }
  __syncthreads();

  f32x2 PX[8], PY[8], PZ[8], DD[8];
#pragma unroll
  for (int p=0;p<8;p++){                    // static indices only
    float4 a = pl[tid + 256*p];             // j=p      (x-half)
    float4 c = pl[tid + 256*(p+8)];         // j=p+8    (y-half)
    PX[p] = (f32x2){a.x, c.x};
    PY[p] = (f32x2){a.y, c.y};
    PZ[p] = (f32x2){a.z, c.z};
    DD[p] = (f32x2){FLT_MAX, FLT_MAX};
  }

  for (int t=1;t<M_;t++){
    f32x2 lxv=(f32x2){lx,lx}, lyv=(f32x2){ly,ly}, lzv=(f32x2){lz,lz};
    f32x2 bd2=(f32x2){-FLT_MAX,-FLT_MAX};
    int bpx=0, bpy=0;
#pragma unroll
    for (int p=0;p<8;p++){                  // verbatim r2 packed body (proven bits)
      f32x2 dx=PX[p]-lxv, dy=PY[p]-lyv, dz=PZ[p]-lzv;
      f32x2 m1=dx*dx, m2=dy*dy, m3=dz*dz;
      f32x2 s=(m1+m2)+m3;                   // same op order as scalar _rn chain
      f32x2 nd=__builtin_elementwise_min(DD[p], s);
      DD[p]=nd;
      if (nd.x>bd2.x){ bd2.x=nd.x; bpx=p; } // strict > keeps smallest p
      if (nd.y>bd2.y){ bd2.y=nd.y; bpy=p; }
    }
    bool ywin = (bd2.y > bd2.x);            // tie -> x-half (smaller idx)
    float bd = ywin ? bd2.y : bd2.x;
    int   bi = tid + 256*(ywin ? bpy+8 : bpx);
    float4 myc = pl[bi];                    // speculative own-candidate read
    unsigned db=__float_as_uint(bd);        // bd>=0 => raw bits order-monotone
    unsigned smax=wave_max_u32(db);
    unsigned cand=(db==smax)?(unsigned)bi:0x7FFFFFFFu;
    unsigned sbi=wave_min_u32(cand);
    if ((unsigned)tid==(sbi&255u)){
      kkey[t&1][wv]=((unsigned long long)smax<<32)|(unsigned)(0xFFFFFFFFu-sbi);
      kxyz[t&1][wv]=myc;
    }
    __syncthreads();
    const unsigned long long* kp=kkey[t&1];
    const float4* cp=kxyz[t&1];
    unsigned long long k0=kp[0],k1=kp[1],k2=kp[2],k3=kp[3];
    float4 c0=cp[0],c1=cp[1],c2=cp[2],c3=cp[3];
    if (k1>k0){ k0=k1; c0=c1; }
    if (k3>k2){ k2=k3; c2=c3; }
    if (k2>k0){ k0=k2; c0=c2; }
    lx=c0.x; ly=c0.y; lz=c0.z;
    if (tid==0){ clist[t][0]=lx; clist[t][1]=ly; clist[t][2]=lz; }
  }
  __syncthreads();
  for (int e=tid; e<M_; e+=256){
    size_t cb=((size_t)b*M_+(size_t)e)*3;
    outc[cb]=clist[e][0]; outc[cb+1]=clist[e][1]; outc[cb+2]=clist[e][2];
  }
}

// ---------------------------------------------------------------- KNN
// PROVEN wave-parallel-refill version (r11).
__global__ __launch_bounds__(256) void knn_kernel(
    const float* __restrict__ xyz, const float* __restrict__ outc,
    u16t* __restrict__ gidx16)
{
  const int w = blockIdx.x*4 + (threadIdx.x>>6);
  const int lane = threadIdx.x & 63;
  const int b = w >> 10;
  const float* xb = xyz + (size_t)b*(N_*3);
  float cx=outc[(size_t)w*3], cy=outc[(size_t)w*3+1], cz=outc[(size_t)w*3+2];
  float c2=__fadd_rn(__fadd_rn(__fmul_rn(cx,cx),__fmul_rn(cy,cy)),__fmul_rn(cz,cz));

  float lv=FLT_MAX; int lj=0;
#pragma unroll
  for (int j=0;j<64;j++){
    int i = lane + 64*j;
    float xx=xb[i*3], xy=xb[i*3+1], xz=xb[i*3+2];
    float x2=__fadd_rn(__fadd_rn(__fmul_rn(xx,xx),__fmul_rn(xy,xy)),__fmul_rn(xz,xz));
    float dt=__fadd_rn(__fadd_rn(__fmul_rn(cx,xx),__fmul_rn(cy,xy)),__fmul_rn(cz,xz));
    float d=__fsub_rn(__fadd_rn(c2,x2),__fmul_rn(2.f,dt));
    if (d<lv){ lv=d; lj=j; }               // strict <: smallest j attaining min
  }
  unsigned long long cons = 0ull;          // my consumed slots
  const int wb = w*K_;
  for (int k=0;k<K_;k++){
    unsigned u=__float_as_uint(lv);
    u = (u&0x80000000u) ? ~u : (u|0x80000000u);   // order-preserving transform
    unsigned smin=wave_min_u32(u);
    unsigned cand=(u==smin)?(unsigned)(lane+64*lj):0xFFFFFFFFu;
    unsigned widx=wave_min_u32(cand);
    if (lane==0) gidx16[wb+k]=(u16t)widx;
    int owner=(int)(widx & 63u);
    int slot =(int)(widx >> 6);
    if (lane==owner) cons |= (1ull<<(unsigned)slot);
    if (k==K_-1) break;                    // nothing consumes the last refill
    unsigned clo=(unsigned)__builtin_amdgcn_readlane((int)(unsigned)cons, owner);
    unsigned chi=(unsigned)__builtin_amdgcn_readlane((int)(unsigned)(cons>>32), owner);
    unsigned long long ocons=((unsigned long long)chi<<32)|(unsigned long long)clo;
    int ip = owner + 64*lane;
    float xx=xb[ip*3], xy=xb[ip*3+1], xz=xb[ip*3+2];
    float x2=__fadd_rn(__fadd_rn(__fmul_rn(xx,xx),__fmul_rn(xy,xy)),__fmul_rn(xz,xz));
    float dt=__fadd_rn(__fadd_rn(__fmul_rn(cx,xx),__fmul_rn(cy,xy)),__fmul_rn(cz,xz));
    float d=__fsub_rn(__fadd_rn(c2,x2),__fmul_rn(2.f,dt));
    unsigned uj=__float_as_uint(d);
    uj=(uj&0x80000000u)?~uj:(uj|0x80000000u);
    if ((ocons>>(unsigned)lane)&1ull) uj=0xFFFFFFFFu;   // exclude consumed
    unsigned smin2=wave_min_u32(uj);
    unsigned cs=(uj==smin2)?(unsigned)lane:64u;
    unsigned sslot=wave_min_u32(cs);                    // smallest slot at min
    float dnew=__uint_as_float((unsigned)__builtin_amdgcn_readlane(__float_as_int(d),(int)sslot));
    if (lane==owner){ lv=dnew; lj=(int)sslot; }
  }
}

// ---------------------------------------------------------------- GEO+FEAT fused launch
// PROVEN (r16). Blocks 0-511 = geo body; 512-767 = feat body (256 thr).
__global__ __launch_bounds__(256) void geofeat_kernel(
    const float* __restrict__ xyz, const float* __restrict__ outc,
    const u16t* __restrict__ gidx16,
    const float* __restrict__ gW1, const float* __restrict__ gWout,
    const float* __restrict__ feats,
    const float* __restrict__ fW1, const float* __restrict__ fb1,
    const float* __restrict__ fWout, const float* __restrict__ fbout,
    float* __restrict__ xout)
{
  __shared__ float smem[160*33 + 64*128 + 32];   // 54.0 KB
  const int t=threadIdx.x;
  if (blockIdx.x < 512){
    // ------------------------------ GEO body (proven, verbatim)
    float (*Es)[33]  = (float(*)[33])smem;
    float (*Hs)[33]  = (float(*)[33])smem;
    float (*Ws)[128] = (float(*)[128])(smem + 160*33);
    float* ssv = smem + 160*33 + 64*128;

    const int g0=blockIdx.x*32;
    for (int p=t; p<1024; p+=256){
      int g=p>>5, kk=p&31;
      int gg=g0+g, b=gg>>10;
      int idx=gidx16[gg*K_+kk];
      const float* pt = xyz + ((size_t)b*N_+(size_t)idx)*3;
      const float* cc = outc + (size_t)gg*3;
      float dx=__fsub_rn(pt[0],cc[0]);
      float dy=__fsub_rn(pt[1],cc[1]);
      float dz=__fsub_rn(pt[2],cc[2]);
      float sq=__fadd_rn(__fadd_rn(__fmul_rn(dx,dx),__fmul_rn(dy,dy)),__fmul_rn(dz,dz));
      int r=5*kk;
      Es[r][g]=dx; Es[r+1][g]=dy; Es[r+2][g]=dz;
      Es[r+3][g]=-1.f; Es[r+4][g]=__fmul_rn(-0.5f,sq);
    }
    const int gsub=t>>4, hsub=t&15, h0=hsub*8;
    const int hw=t>>1;
    float acc[2][8];
#pragma unroll
    for (int a=0;a<2;a++)
#pragma unroll
      for (int j=0;j<8;j++) acc[a][j]=0.f;
    __syncthreads();

    for (int c=0;c<3;c++){
      int i0=c*64;
      if (c<2){
        int fw0=(t&1)*32;
        const float* wr = gW1 + (size_t)hw*GEO_IN_ + i0 + fw0;
        float4 wv[8];
#pragma unroll
        for (int e=0;e<8;e++) wv[e]=((const float4*)wr)[e];
#pragma unroll
        for (int e=0;e<8;e++){
          Ws[fw0+4*e+0][hw]=wv[e].x;
          Ws[fw0+4*e+1][hw]=wv[e].y;
          Ws[fw0+4*e+2][hw]=wv[e].z;
          Ws[fw0+4*e+3][hw]=wv[e].w;
        }
      } else {
        int fw0=(t&1)*16;
        const float* wr = gW1 + (size_t)hw*GEO_IN_ + 128 + fw0;
        float4 wv[4];
#pragma unroll
        for (int e=0;e<4;e++) wv[e]=((const float4*)wr)[e];
#pragma unroll
        for (int e=0;e<4;e++){
          Ws[fw0+4*e+0][hw]=wv[e].x;
          Ws[fw0+4*e+1][hw]=wv[e].y;
          Ws[fw0+4*e+2][hw]=wv[e].z;
          Ws[fw0+4*e+3][hw]=wv[e].w;
        }
      }
      __syncthreads();
      int len=(c==2)?32:64;
      for (int k2=0;k2<len;k2++){
        float x0=Es[i0+k2][2*gsub], x1=Es[i0+k2][2*gsub+1];
        const float* wp=&Ws[k2][h0];
        float4 wa=*(const float4*)wp;
        float4 wb=*(const float4*)(wp+4);
        acc[0][0]=__builtin_fmaf(x0,wa.x,acc[0][0]);
        acc[0][1]=__builtin_fmaf(x0,wa.y,acc[0][1]);
        acc[0][2]=__builtin_fmaf(x0,wa.z,acc[0][2]);
        acc[0][3]=__builtin_fmaf(x0,wa.w,acc[0][3]);
        acc[0][4]=__builtin_fmaf(x0,wb.x,acc[0][4]);
        acc[0][5]=__builtin_fmaf(x0,wb.y,acc[0][5]);
        acc[0][6]=__builtin_fmaf(x0,wb.z,acc[0][6]);
        acc[0][7]=__builtin_fmaf(x0,wb.w,acc[0][7]);
        acc[1][0]=__builtin_fmaf(x1,wa.x,acc[1][0]);
        acc[1][1]=__builtin_fmaf(x1,wa.y,acc[1][1]);
        acc[1][2]=__builtin_fmaf(x1,wa.z,acc[1][2]);
        acc[1][3]=__builtin_fmaf(x1,wa.w,acc[1][3]);
        acc[1][4]=__builtin_fmaf(x1,wb.x,acc[1][4]);
        acc[1][5]=__builtin_fmaf(x1,wb.y,acc[1][5]);
        acc[1][6]=__builtin_fmaf(x1,wb.z,acc[1][6]);
        acc[1][7]=__builtin_fmaf(x1,wb.w,acc[1][7]);
      }
      __syncthreads();
    }
#pragma unroll
    for (int a=0;a<2;a++)
#pragma unroll
      for (int j=0;j<8;j++)
        Hs[h0+j][2*gsub+a]=acc[a][j];
    __syncthreads();
    if (t<32){
      float ss=0.f;
      for (int h=0;h<H_;h++){ float v=Hs[h][t]; ss=__builtin_fmaf(v,v,ss); }
      ssv[t]=__fmul_rn(-0.5f,ss);
    }
#pragma unroll
    for (int a=0;a<2;a++)
#pragma unroll
      for (int j=0;j<8;j++) acc[a][j]=0.f;
    for (int c=0;c<2;c++){
      int i0=c*64;
      int fw0=(t&1)*32;
      const float* wr = gWout + (size_t)hw*GEO_MID_ + i0 + fw0;
      float2 wv2[16];
#pragma unroll
      for (int e=0;e<16;e++) wv2[e]=((const float2*)wr)[e];
      __syncthreads();
#pragma unroll
      for (int e=0;e<16;e++){
        Ws[fw0+2*e+0][hw]=wv2[e].x;
        Ws[fw0+2*e+1][hw]=wv2[e].y;
      }
      __syncthreads();
      for (int k2=0;k2<64;k2++){
        float x0=Hs[i0+k2][2*gsub], x1=Hs[i0+k2][2*gsub+1];
        const float* wp=&Ws[k2][h0];
        float4 wa=*(const float4*)wp;
        float4 wb=*(const float4*)(wp+4);
        acc[0][0]=__builtin_fmaf(x0,wa.x,acc[0][0]);
        acc[0][1]=__builtin_fmaf(x0,wa.y,acc[0][1]);
        acc[0][2]=__builtin_fmaf(x0,wa.z,acc[0][2]);
        acc[0][3]=__builtin_fmaf(x0,wa.w,acc[0][3]);
        acc[0][4]=__builtin_fmaf(x0,wb.x,acc[0][4]);
        acc[0][5]=__builtin_fmaf(x0,wb.y,acc[0][5]);
        acc[0][6]=__builtin_fmaf(x0,wb.z,acc[0][6]);
        acc[0][7]=__builtin_fmaf(x0,wb.w,acc[0][7]);
        acc[1][0]=__builtin_fmaf(x1,wa.x,acc[1][0]);
        acc[1][1]=__builtin_fmaf(x1,wa.y,acc[1][1]);
        acc[1][2]=__builtin_fmaf(x1,wa.z,acc[1][2]);
        acc[1][3]=__builtin_fmaf(x1,wa.w,acc[1][3]);
        acc[1][4]=__builtin_fmaf(x1,wb.x,acc[1][4]);
        acc[1][5]=__builtin_fmaf(x1,wb.y,acc[1][5]);
        acc[1][6]=__builtin_fmaf(x1,wb.z,acc[1][6]);
        acc[1][7]=__builtin_fmaf(x1,wb.w,acc[1][7]);
      }
    }
#pragma unroll
    for (int j=0;j<8;j++){
      int o=h0+j;
      float2 we=*(const float2*)(gWout + (size_t)o*GEO_MID_ + 128);
#pragma unroll
      for (int a=0;a<2;a++){
        float v=acc[a][j];
        v=__builtin_fmaf(-1.f, we.x, v);
        v=__builtin_fmaf(ssv[2*gsub+a], we.y, v);
        xout[(size_t)(g0+2*gsub+a)*256 + o]=v;
      }
    }
  } else {
    // ------------------------------ FEAT body (proven r12 256-thr, verbatim)
    float (*Xs)[68]  = (float(*)[68])smem;             // [64][68]
    float (*Ws)[128] = (float(*)[128])(smem + 64*68);  // [64][128]
    float (*Hs)[68]  = (float(*)[68])smem;             // [128][68] alias
    float (*WoS)[128]= (float(*)[128])(smem + 128*68); // [32][128]
    const int g0=(blockIdx.x-512)*64;
    const int gsub=t>>4;
    const int h0=(t&15)*8;
    const int glx=t>>2, fq=(t&3)*16;
    const int hw=t>>1, fw0=(t&1)*32;
    const int fw1=(t&1)*16;
    const int gld=g0+glx, bld=gld>>10;
    float acc[4][8];
#pragma unroll
    for (int a=0;a<4;a++)
#pragma unroll
      for (int j=0;j<8;j++) acc[a][j]=0.f;

    for (int kk=0;kk<K_;kk++){
      int nidx=gidx16[gld*K_+kk];
      const float* fr=feats + ((size_t)bld*N_+(size_t)nidx)*FEAT_ + fq;
      float4 p[4];
#pragma unroll
      for (int e=0;e<4;e++) p[e]=((const float4*)fr)[e];
      const float* wr=fW1 + (size_t)hw*FEAT_IN_ + kk*64 + fw0;
      float4 wv[8];
#pragma unroll
      for (int e=0;e<8;e++) wv[e]=((const float4*)wr)[e];
#pragma unroll
      for (int e=0;e<4;e++){
        Xs[fq+4*e+0][glx]=p[e].x;
        Xs[fq+4*e+1][glx]=p[e].y;
        Xs[fq+4*e+2][glx]=p[e].z;
        Xs[fq+4*e+3][glx]=p[e].w;
      }
#pragma unroll
      for (int e=0;e<8;e++){
        Ws[fw0+4*e+0][hw]=wv[e].x;
        Ws[fw0+4*e+1][hw]=wv[e].y;
        Ws[fw0+4*e+2][hw]=wv[e].z;
        Ws[fw0+4*e+3][hw]=wv[e].w;
      }
      __syncthreads();
#pragma unroll 4
      for (int k2=0;k2<64;k2++){
        float4 xv=*(const float4*)&Xs[k2][4*gsub];
        const float* wp=&Ws[k2][h0];
        float4 wa=*(const float4*)wp;
        float4 wb=*(const float4*)(wp+4);
        float xr[4]={xv.x,xv.y,xv.z,xv.w};
        float wf[8]={wa.x,wa.y,wa.z,wa.w,wb.x,wb.y,wb.z,wb.w};
#pragma unroll
        for (int a=0;a<4;a++)
#pragma unroll
          for (int j=0;j<8;j++)
            acc[a][j]=__builtin_fmaf(xr[a],wf[j],acc[a][j]);
      }
      __syncthreads();
    }
#pragma unroll
    for (int j=0;j<8;j++){
      float bv=fb1[h0+j];
#pragma unroll
      for (int a=0;a<4;a++)
        Hs[h0+j][4*gsub+a]=fmaxf(__fadd_rn(acc[a][j],bv),0.f);
    }
    float ac2[4][8];
#pragma unroll
    for (int a=0;a<4;a++)
#pragma unroll
      for (int j=0;j<8;j++) ac2[a][j]=0.f;
    for (int c=0;c<4;c++){
      const float* wr2=fWout + (size_t)hw*H_ + c*32 + fw1;
      float4 w2[4];
#pragma unroll
      for (int e=0;e<4;e++) w2[e]=((const float4*)wr2)[e];
      __syncthreads();
#pragma unroll
      for (int e=0;e<4;e++){
        WoS[fw1+4*e+0][hw]=w2[e].x;
        WoS[fw1+4*e+1][hw]=w2[e].y;
        WoS[fw1+4*e+2][hw]=w2[e].z;
        WoS[fw1+4*e+3][hw]=w2[e].w;
      }
      __syncthreads();
#pragma unroll 4
      for (int k2=0;k2<32;k2++){
        float4 xv=*(const float4*)&Hs[c*32+k2][4*gsub];
        const float* wp=&WoS[k2][h0];
        float4 wa=*(const float4*)wp;
        float4 wb=*(const float4*)(wp+4);
        float xr[4]={xv.x,xv.y,xv.z,xv.w};
        float wf[8]={wa.x,wa.y,wa.z,wa.w,wb.x,wb.y,wb.z,wb.w};
#pragma unroll
        for (int a=0;a<4;a++)
#pragma unroll
          for (int j=0;j<8;j++)
            ac2[a][j]=__builtin_fmaf(xr[a],wf[j],ac2[a][j]);
      }
    }
#pragma unroll
    for (int j=0;j<8;j++){
      float bv=fbout[h0+j];
#pragma unroll
      for (int a=0;a<4;a++)
        xout[(size_t)(g0+4*gsub+a)*256+128+h0+j]=__fadd_rn(ac2[a][j],bv);
    }
  }
}

// ----------------------------------------------------------------
extern "C" void kernel_launch(void* const* d_in, const int* in_sizes, int n_in,
                              void* d_out, int out_size, void* d_ws, size_t ws_size,
                              hipStream_t stream) {
  const float* xyz  =(const float*)d_in[0];
  const float* feats=(const float*)d_in[1];
  const float* gW1  =(const float*)d_in[2];
  const float* gWout=(const float*)d_in[3];
  const float* fW1  =(const float*)d_in[4];
  const float* fb1  =(const float*)d_in[5];
  const float* fWout=(const float*)d_in[6];
  const float* fbout=(const float*)d_in[7];
  float* out=(float*)d_out;

  u16t* gidx16=(u16t*)d_ws;          // 1 MB
  float* xout = out + (size_t)B_*M_*3;

  fps_kernel    <<<dim3(B_),        dim3(256), 0, stream>>>(xyz, out);
  knn_kernel    <<<dim3((B_*M_)/4), dim3(256), 0, stream>>>(xyz, out, gidx16);
  geofeat_kernel<<<dim3(768),       dim3(256), 0, stream>>>(
      xyz, out, gidx16, gW1, gWout, feats, fW1, fb1, fWout, fbout, xout);
}

// Round 20
// 984.375 us; speedup vs baseline: 1.9226x; 1.0929x over previous
//
#include <hip/hip_runtime.h>
#include <float.h>

#pragma clang fp contract(off)

#define B_ 16
#define N_ 4096
#define M_ 1024
#define K_ 32
#define FEAT_ 64
#define H_ 128
#define GEO_IN_ 160
#define GEO_MID_ 130
#define FEAT_IN_ 2048

typedef unsigned short u16t;
typedef float f32x2 __attribute__((ext_vector_type(2)));
typedef short bf16x8 __attribute__((ext_vector_type(8)));   // 8 bf16 (4 VGPRs)
typedef float f32x4 __attribute__((ext_vector_type(4)));    // MFMA acc

// RNE float->bf16 (normal inputs; matches standard rounding)
__device__ __forceinline__ unsigned short f2bf(float f){
  unsigned x = __float_as_uint(f);
  unsigned r = x + 0x7FFFu + ((x>>16)&1u);
  return (unsigned short)(r>>16);
}
__device__ __forceinline__ unsigned pkbf(float lo, float hi){
  return (unsigned)f2bf(lo) | ((unsigned)f2bf(hi)<<16);
}

// ---- wave64 reductions in the VALU pipe (DPP), identity-preserving ----
#define DPP_STEP_MAX(ctrl) \
  t=(unsigned)__builtin_amdgcn_update_dpp((int)v,(int)v,(ctrl),0xf,0xf,false); \
  v=(t>v)?t:v;
#define DPP_STEP_MIN(ctrl) \
  t=(unsigned)__builtin_amdgcn_update_dpp((int)v,(int)v,(ctrl),0xf,0xf,false); \
  v=(t<v)?t:v;

__device__ __forceinline__ unsigned wave_max_u32(unsigned v){
  unsigned t;
  DPP_STEP_MAX(0x111) DPP_STEP_MAX(0x112) DPP_STEP_MAX(0x114) DPP_STEP_MAX(0x118)
  DPP_STEP_MAX(0x142) DPP_STEP_MAX(0x143)
  return (unsigned)__builtin_amdgcn_readlane((int)v,63);
}
__device__ __forceinline__ unsigned wave_min_u32(unsigned v){
  unsigned t;
  DPP_STEP_MIN(0x111) DPP_STEP_MIN(0x112) DPP_STEP_MIN(0x114) DPP_STEP_MIN(0x118)
  DPP_STEP_MIN(0x142) DPP_STEP_MIN(0x143)
  return (unsigned)__builtin_amdgcn_readlane((int)v,63);
}

// ---------------------------------------------------------------- FPS v4
// PROVEN (653us, verified r12/r14/r16/r19). FROZEN.
__global__ __launch_bounds__(256) void fps_kernel(
    const float* __restrict__ xyz, float* __restrict__ outc)
{
  const int b = blockIdx.x, tid = threadIdx.x;
  const int wv = tid >> 6;
  const float* xb = xyz + (size_t)b * (N_*3);
  __shared__ __align__(16) float4 pl[N_];   // 64 KB staged xyz
  __shared__ unsigned long long kkey[2][4];
  __shared__ __align__(16) float4 kxyz[2][4];
  __shared__ float clist[M_][3];            // 12 KB

  for (int i=tid; i<N_; i+=256)
    pl[i] = make_float4(xb[i*3], xb[i*3+1], xb[i*3+2], 0.f);
  float lx=xb[0], ly=xb[1], lz=xb[2];
  if (tid==0){ clist[0][0]=lx; clist[0][1]=ly; clist[0][2]=lz; }
  __syncthreads();

  f32x2 PX[8], PY[8], PZ[8], DD[8];
#pragma unroll
  for (int p=0;p<8;p++){                    // static indices only
    float4 a = pl[tid + 256*p];             // j=p      (x-half)
    float4 c = pl[tid + 256*(p+8)];         // j=p+8    (y-half)
    PX[p] = (f32x2){a.x, c.x};
    PY[p] = (f32x2){a.y, c.y};
    PZ[p] = (f32x2){a.z, c.z};
    DD[p] = (f32x2){FLT_MAX, FLT_MAX};
  }

  for (int t=1;t<M_;t++){
    f32x2 lxv=(f32x2){lx,lx}, lyv=(f32x2){ly,ly}, lzv=(f32x2){lz,lz};
    f32x2 bd2=(f32x2){-FLT_MAX,-FLT_MAX};
    int bpx=0, bpy=0;
#pragma unroll
    for (int p=0;p<8;p++){                  // verbatim r2 packed body (proven bits)
      f32x2 dx=PX[p]-lxv, dy=PY[p]-lyv, dz=PZ[p]-lzv;
      f32x2 m1=dx*dx, m2=dy*dy, m3=dz*dz;
      f32x2 s=(m1+m2)+m3;                   // same op order as scalar _rn chain
      f32x2 nd=__builtin_elementwise_min(DD[p], s);
      DD[p]=nd;
      if (nd.x>bd2.x){ bd2.x=nd.x; bpx=p; } // strict > keeps smallest p
      if (nd.y>bd2.y){ bd2.y=nd.y; bpy=p; }
    }
    bool ywin = (bd2.y > bd2.x);            // tie -> x-half (smaller idx)
    float bd = ywin ? bd2.y : bd2.x;
    int   bi = tid + 256*(ywin ? bpy+8 : bpx);
    float4 myc = pl[bi];                    // speculative own-candidate read
    unsigned db=__float_as_uint(bd);        // bd>=0 => raw bits order-monotone
    unsigned smax=wave_max_u32(db);
    unsigned cand=(db==smax)?(unsigned)bi:0x7FFFFFFFu;
    unsigned sbi=wave_min_u32(cand);
    if ((unsigned)tid==(sbi&255u)){
      kkey[t&1][wv]=((unsigned long long)smax<<32)|(unsigned)(0xFFFFFFFFu-sbi);
      kxyz[t&1][wv]=myc;
    }
    __syncthreads();
    const unsigned long long* kp=kkey[t&1];
    const float4* cp=kxyz[t&1];
    unsigned long long k0=kp[0],k1=kp[1],k2=kp[2],k3=kp[3];
    float4 c0=cp[0],c1=cp[1],c2=cp[2],c3=cp[3];
    if (k1>k0){ k0=k1; c0=c1; }
    if (k3>k2){ k2=k3; c2=c3; }
    if (k2>k0){ k0=k2; c0=c2; }
    lx=c0.x; ly=c0.y; lz=c0.z;
    if (tid==0){ clist[t][0]=lx; clist[t][1]=ly; clist[t][2]=lz; }
  }
  __syncthreads();
  for (int e=tid; e<M_; e+=256){
    size_t cb=((size_t)b*M_+(size_t)e)*3;
    outc[cb]=clist[e][0]; outc[cb+1]=clist[e][1]; outc[cb+2]=clist[e][2];
  }
}

// ---------------------------------------------------------------- KNN
// PROVEN wave-parallel-refill version (r11).
__global__ __launch_bounds__(256) void knn_kernel(
    const float* __restrict__ xyz, const float* __restrict__ outc,
    u16t* __restrict__ gidx16)
{
  const int w = blockIdx.x*4 + (threadIdx.x>>6);
  const int lane = threadIdx.x & 63;
  const int b = w >> 10;
  const float* xb = xyz + (size_t)b*(N_*3);
  float cx=outc[(size_t)w*3], cy=outc[(size_t)w*3+1], cz=outc[(size_t)w*3+2];
  float c2=__fadd_rn(__fadd_rn(__fmul_rn(cx,cx),__fmul_rn(cy,cy)),__fmul_rn(cz,cz));

  float lv=FLT_MAX; int lj=0;
#pragma unroll
  for (int j=0;j<64;j++){
    int i = lane + 64*j;
    float xx=xb[i*3], xy=xb[i*3+1], xz=xb[i*3+2];
    float x2=__fadd_rn(__fadd_rn(__fmul_rn(xx,xx),__fmul_rn(xy,xy)),__fmul_rn(xz,xz));
    float dt=__fadd_rn(__fadd_rn(__fmul_rn(cx,xx),__fmul_rn(cy,xy)),__fmul_rn(cz,xz));
    float d=__fsub_rn(__fadd_rn(c2,x2),__fmul_rn(2.f,dt));
    if (d<lv){ lv=d; lj=j; }               // strict <: smallest j attaining min
  }
  unsigned long long cons = 0ull;          // my consumed slots
  const int wb = w*K_;
  for (int k=0;k<K_;k++){
    unsigned u=__float_as_uint(lv);
    u = (u&0x80000000u) ? ~u : (u|0x80000000u);   // order-preserving transform
    unsigned smin=wave_min_u32(u);
    unsigned cand=(u==smin)?(unsigned)(lane+64*lj):0xFFFFFFFFu;
    unsigned widx=wave_min_u32(cand);
    if (lane==0) gidx16[wb+k]=(u16t)widx;
    int owner=(int)(widx & 63u);
    int slot =(int)(widx >> 6);
    if (lane==owner) cons |= (1ull<<(unsigned)slot);
    if (k==K_-1) break;                    // nothing consumes the last refill
    unsigned clo=(unsigned)__builtin_amdgcn_readlane((int)(unsigned)cons, owner);
    unsigned chi=(unsigned)__builtin_amdgcn_readlane((int)(unsigned)(cons>>32), owner);
    unsigned long long ocons=((unsigned long long)chi<<32)|(unsigned long long)clo;
    int ip = owner + 64*lane;
    float xx=xb[ip*3], xy=xb[ip*3+1], xz=xb[ip*3+2];
    float x2=__fadd_rn(__fadd_rn(__fmul_rn(xx,xx),__fmul_rn(xy,xy)),__fmul_rn(xz,xz));
    float dt=__fadd_rn(__fadd_rn(__fmul_rn(cx,xx),__fmul_rn(cy,xy)),__fmul_rn(cz,xz));
    float d=__fsub_rn(__fadd_rn(c2,x2),__fmul_rn(2.f,dt));
    unsigned uj=__float_as_uint(d);
    uj=(uj&0x80000000u)?~uj:(uj|0x80000000u);
    if ((ocons>>(unsigned)lane)&1ull) uj=0xFFFFFFFFu;   // exclude consumed
    unsigned smin2=wave_min_u32(uj);
    unsigned cs=(uj==smin2)?(unsigned)lane:64u;
    unsigned sslot=wave_min_u32(cs);                    // smallest slot at min
    float dnew=__uint_as_float((unsigned)__builtin_amdgcn_readlane(__float_as_int(d),(int)sslot));
    if (lane==owner){ lv=dnew; lj=(int)sslot; }
  }
}

// ---------------------------------------------------------------- GEO+FEAT fused launch
// Blocks 0-511 = PROVEN geo body (fp32, unchanged). Blocks 512-767 = FEAT
// rewritten as bf16 MFMA GEMM: [64 grp x 2048] @ W1^T -> relu+b -> @ Wout^T.
// Per block: 4 waves; wave w owns M-strip 16 rows; per neighbor kk stage
// X(64x64) bf16 row-major [64][72] + W1 slice TRANSPOSED [n][k] [128][72]
// (B-frag = contiguous 16B read; +8 pad => 2-way bank conflict = free).
// mfma_f32_16x16x32_bf16: A lane=(l&15) row,(l>>4)*8 k; B lane=(l&15) col;
// C/D col=l&15,row=(l>>4)*4+reg (m89-verified). GEMM2: H [64][136] bf16 +
// Wout [o][h]=[128][136] (natural B-transposed layout). fp32 MFMA accum;
// bf16 input quantization ~<=0.15 abs on O(1-5) outputs vs 0.43 margin.
__global__ __launch_bounds__(256) void geofeat_kernel(
    const float* __restrict__ xyz, const float* __restrict__ outc,
    const u16t* __restrict__ gidx16,
    const float* __restrict__ gW1, const float* __restrict__ gWout,
    const float* __restrict__ feats,
    const float* __restrict__ fW1, const float* __restrict__ fb1,
    const float* __restrict__ fWout, const float* __restrict__ fbout,
    float* __restrict__ xout)
{
  __shared__ __align__(16) float smem[160*33 + 64*128 + 32];   // 54.4 KB
  const int t=threadIdx.x;
  if (blockIdx.x < 512){
    // ------------------------------ GEO body (proven, verbatim)
    float (*Es)[33]  = (float(*)[33])smem;
    float (*Hs)[33]  = (float(*)[33])smem;
    float (*Ws)[128] = (float(*)[128])(smem + 160*33);
    float* ssv = smem + 160*33 + 64*128;

    const int g0=blockIdx.x*32;
    for (int p=t; p<1024; p+=256){
      int g=p>>5, kk=p&31;
      int gg=g0+g, b=gg>>10;
      int idx=gidx16[gg*K_+kk];
      const float* pt = xyz + ((size_t)b*N_+(size_t)idx)*3;
      const float* cc = outc + (size_t)gg*3;
      float dx=__fsub_rn(pt[0],cc[0]);
      float dy=__fsub_rn(pt[1],cc[1]);
      float dz=__fsub_rn(pt[2],cc[2]);
      float sq=__fadd_rn(__fadd_rn(__fmul_rn(dx,dx),__fmul_rn(dy,dy)),__fmul_rn(dz,dz));
      int r=5*kk;
      Es[r][g]=dx; Es[r+1][g]=dy; Es[r+2][g]=dz;
      Es[r+3][g]=-1.f; Es[r+4][g]=__fmul_rn(-0.5f,sq);
    }
    const int gsub=t>>4, hsub=t&15, h0=hsub*8;
    const int hw=t>>1;
    float acc[2][8];
#pragma unroll
    for (int a=0;a<2;a++)
#pragma unroll
      for (int j=0;j<8;j++) acc[a][j]=0.f;
    __syncthreads();

    for (int c=0;c<3;c++){
      int i0=c*64;
      if (c<2){
        int fw0=(t&1)*32;
        const float* wr = gW1 + (size_t)hw*GEO_IN_ + i0 + fw0;
        float4 wv[8];
#pragma unroll
        for (int e=0;e<8;e++) wv[e]=((const float4*)wr)[e];
#pragma unroll
        for (int e=0;e<8;e++){
          Ws[fw0+4*e+0][hw]=wv[e].x;
          Ws[fw0+4*e+1][hw]=wv[e].y;
          Ws[fw0+4*e+2][hw]=wv[e].z;
          Ws[fw0+4*e+3][hw]=wv[e].w;
        }
      } else {
        int fw0=(t&1)*16;
        const float* wr = gW1 + (size_t)hw*GEO_IN_ + 128 + fw0;
        float4 wv[4];
#pragma unroll
        for (int e=0;e<4;e++) wv[e]=((const float4*)wr)[e];
#pragma unroll
        for (int e=0;e<4;e++){
          Ws[fw0+4*e+0][hw]=wv[e].x;
          Ws[fw0+4*e+1][hw]=wv[e].y;
          Ws[fw0+4*e+2][hw]=wv[e].z;
          Ws[fw0+4*e+3][hw]=wv[e].w;
        }
      }
      __syncthreads();
      int len=(c==2)?32:64;
      for (int k2=0;k2<len;k2++){
        float x0=Es[i0+k2][2*gsub], x1=Es[i0+k2][2*gsub+1];
        const float* wp=&Ws[k2][h0];
        float4 wa=*(const float4*)wp;
        float4 wb=*(const float4*)(wp+4);
        acc[0][0]=__builtin_fmaf(x0,wa.x,acc[0][0]);
        acc[0][1]=__builtin_fmaf(x0,wa.y,acc[0][1]);
        acc[0][2]=__builtin_fmaf(x0,wa.z,acc[0][2]);
        acc[0][3]=__builtin_fmaf(x0,wa.w,acc[0][3]);
        acc[0][4]=__builtin_fmaf(x0,wb.x,acc[0][4]);
        acc[0][5]=__builtin_fmaf(x0,wb.y,acc[0][5]);
        acc[0][6]=__builtin_fmaf(x0,wb.z,acc[0][6]);
        acc[0][7]=__builtin_fmaf(x0,wb.w,acc[0][7]);
        acc[1][0]=__builtin_fmaf(x1,wa.x,acc[1][0]);
        acc[1][1]=__builtin_fmaf(x1,wa.y,acc[1][1]);
        acc[1][2]=__builtin_fmaf(x1,wa.z,acc[1][2]);
        acc[1][3]=__builtin_fmaf(x1,wa.w,acc[1][3]);
        acc[1][4]=__builtin_fmaf(x1,wb.x,acc[1][4]);
        acc[1][5]=__builtin_fmaf(x1,wb.y,acc[1][5]);
        acc[1][6]=__builtin_fmaf(x1,wb.z,acc[1][6]);
        acc[1][7]=__builtin_fmaf(x1,wb.w,acc[1][7]);
      }
      __syncthreads();
    }
#pragma unroll
    for (int a=0;a<2;a++)
#pragma unroll
      for (int j=0;j<8;j++)
        Hs[h0+j][2*gsub+a]=acc[a][j];
    __syncthreads();
    if (t<32){
      float ss=0.f;
      for (int h=0;h<H_;h++){ float v=Hs[h][t]; ss=__builtin_fmaf(v,v,ss); }
      ssv[t]=__fmul_rn(-0.5f,ss);
    }
#pragma unroll
    for (int a=0;a<2;a++)
#pragma unroll
      for (int j=0;j<8;j++) acc[a][j]=0.f;
    for (int c=0;c<2;c++){
      int i0=c*64;
      int fw0=(t&1)*32;
      const float* wr = gWout + (size_t)hw*GEO_MID_ + i0 + fw0;
      float2 wv2[16];
#pragma unroll
      for (int e=0;e<16;e++) wv2[e]=((const float2*)wr)[e];
      __syncthreads();
#pragma unroll
      for (int e=0;e<16;e++){
        Ws[fw0+2*e+0][hw]=wv2[e].x;
        Ws[fw0+2*e+1][hw]=wv2[e].y;
      }
      __syncthreads();
      for (int k2=0;k2<64;k2++){
        float x0=Hs[i0+k2][2*gsub], x1=Hs[i0+k2][2*gsub+1];
        const float* wp=&Ws[k2][h0];
        float4 wa=*(const float4*)wp;
        float4 wb=*(const float4*)(wp+4);
        acc[0][0]=__builtin_fmaf(x0,wa.x,acc[0][0]);
        acc[0][1]=__builtin_fmaf(x0,wa.y,acc[0][1]);
        acc[0][2]=__builtin_fmaf(x0,wa.z,acc[0][2]);
        acc[0][3]=__builtin_fmaf(x0,wa.w,acc[0][3]);
        acc[0][4]=__builtin_fmaf(x0,wb.x,acc[0][4]);
        acc[0][5]=__builtin_fmaf(x0,wb.y,acc[0][5]);
        acc[0][6]=__builtin_fmaf(x0,wb.z,acc[0][6]);
        acc[0][7]=__builtin_fmaf(x0,wb.w,acc[0][7]);
        acc[1][0]=__builtin_fmaf(x1,wa.x,acc[1][0]);
        acc[1][1]=__builtin_fmaf(x1,wa.y,acc[1][1]);
        acc[1][2]=__builtin_fmaf(x1,wa.z,acc[1][2]);
        acc[1][3]=__builtin_fmaf(x1,wa.w,acc[1][3]);
        acc[1][4]=__builtin_fmaf(x1,wb.x,acc[1][4]);
        acc[1][5]=__builtin_fmaf(x1,wb.y,acc[1][5]);
        acc[1][6]=__builtin_fmaf(x1,wb.z,acc[1][6]);
        acc[1][7]=__builtin_fmaf(x1,wb.w,acc[1][7]);
      }
    }
#pragma unroll
    for (int j=0;j<8;j++){
      int o=h0+j;
      float2 we=*(const float2*)(gWout + (size_t)o*GEO_MID_ + 128);
#pragma unroll
      for (int a=0;a<2;a++){
        float v=acc[a][j];
        v=__builtin_fmaf(-1.f, we.x, v);
        v=__builtin_fmaf(ssv[2*gsub+a], we.y, v);
        xout[(size_t)(g0+2*gsub+a)*256 + o]=v;
      }
    }
  } else {
    // ------------------------------ FEAT body: bf16 MFMA GEMM
    short* As  = (short*)smem;                 // [64][72]  bf16 (X chunk)
    short* Bs  = (short*)smem + 64*72;         // [128][72] bf16 (W1^T chunk)
    short* H2  = (short*)smem;                 // [64][136] bf16 (relu H) -- phase2
    short* W2s = (short*)smem + 64*136;        // [128][136] bf16 (Wout)  -- phase2
    const int g0=(blockIdx.x-512)*64;
    const int w = t>>6, l = t&63;
    const int row16 = l&15, kg = l>>4;         // MFMA lane decomposition
    f32x4 acc[8];
#pragma unroll
    for (int f=0; f<8; f++) acc[f] = (f32x4){0.f,0.f,0.f,0.f};

    const int gl = t>>2, fq = (t&3)*16;        // A staging: group x feat-quarter
    const int gg = g0+gl, bld2 = gg>>10;
    const int hR = t>>1, kh = (t&1)*32;        // B staging: W1 row x k-half

    for (int kk=0; kk<K_; kk++){
      // stage A: gathered feats -> bf16 [64][72]
      int nidx = gidx16[gg*K_+kk];
      const float* fr = feats + ((size_t)bld2*N_+(size_t)nidx)*FEAT_ + fq;
      float4 p0=((const float4*)fr)[0], p1=((const float4*)fr)[1],
             p2=((const float4*)fr)[2], p3=((const float4*)fr)[3];
      unsigned* aw = (unsigned*)(As + gl*72 + fq);
      aw[0]=pkbf(p0.x,p0.y); aw[1]=pkbf(p0.z,p0.w);
      aw[2]=pkbf(p1.x,p1.y); aw[3]=pkbf(p1.z,p1.w);
      aw[4]=pkbf(p2.x,p2.y); aw[5]=pkbf(p2.z,p2.w);
      aw[6]=pkbf(p3.x,p3.y); aw[7]=pkbf(p3.z,p3.w);
      // stage B: W1 slice row hR, k-range [kk*64+kh, +32) -> [n][k] bf16
      const float* wr = fW1 + (size_t)hR*FEAT_IN_ + kk*64 + kh;
      unsigned* bw = (unsigned*)(Bs + hR*72 + kh);
#pragma unroll
      for (int e=0;e<8;e++){
        float4 wv=((const float4*)wr)[e];
        bw[2*e+0]=pkbf(wv.x,wv.y);
        bw[2*e+1]=pkbf(wv.z,wv.w);
      }
      __syncthreads();
      const short* Ar = As + (16*w + row16)*72;
#pragma unroll
      for (int s=0; s<2; s++){
        bf16x8 af = *(const bf16x8*)(Ar + s*32 + kg*8);
#pragma unroll
        for (int f=0; f<8; f++){
          bf16x8 bfr = *(const bf16x8*)(Bs + (f*16+row16)*72 + s*32 + kg*8);
          acc[f] = __builtin_amdgcn_mfma_f32_16x16x32_bf16(af, bfr, acc[f], 0,0,0);
        }
      }
      __syncthreads();
    }
    // bias + relu -> H2 bf16 [64][136]
#pragma unroll
    for (int f=0; f<8; f++){
      float bv = fb1[f*16 + row16];
#pragma unroll
      for (int r=0; r<4; r++){
        float v = fmaxf(__fadd_rn(acc[f][r], bv), 0.f);
        H2[(16*w + kg*4 + r)*136 + f*16 + row16] = (short)f2bf(v);
      }
    }
    // stage Wout -> W2s bf16 [128][136] ([o][h] natural layout)
    {
      const int oR = t>>1, hh = (t&1)*64;
      const float* w2r = fWout + (size_t)oR*H_ + hh;
      unsigned* ww = (unsigned*)(W2s + oR*136 + hh);
#pragma unroll
      for (int e=0;e<16;e++){
        float4 wv=((const float4*)w2r)[e];
        ww[2*e+0]=pkbf(wv.x,wv.y);
        ww[2*e+1]=pkbf(wv.z,wv.w);
      }
    }
    __syncthreads();
    // GEMM2: out = H @ Wout^T, K=128
    f32x4 ac2[8];
#pragma unroll
    for (int f=0; f<8; f++) ac2[f] = (f32x4){0.f,0.f,0.f,0.f};
    const short* A2r = H2 + (16*w + row16)*136;
#pragma unroll
    for (int s2=0; s2<4; s2++){
      bf16x8 a2 = *(const bf16x8*)(A2r + s2*32 + kg*8);
#pragma unroll
      for (int f=0; f<8; f++){
        bf16x8 b2 = *(const bf16x8*)(W2s + (f*16+row16)*136 + s2*32 + kg*8);
        ac2[f] = __builtin_amdgcn_mfma_f32_16x16x32_bf16(a2, b2, ac2[f], 0,0,0);
      }
    }
    // write out + bout
#pragma unroll
    for (int f=0; f<8; f++){
      float bo = fbout[f*16 + row16];
#pragma unroll
      for (int r=0; r<4; r++){
        int g = g0 + 16*w + kg*4 + r;
        xout[(size_t)g*256 + 128 + f*16 + row16] = __fadd_rn(ac2[f][r], bo);
      }
    }
  }
}

// ----------------------------------------------------------------
extern "C" void kernel_launch(void* const* d_in, const int* in_sizes, int n_in,
                              void* d_out, int out_size, void* d_ws, size_t ws_size,
                              hipStream_t stream) {
  const float* xyz  =(const float*)d_in[0];
  const float* feats=(const float*)d_in[1];
  const float* gW1  =(const float*)d_in[2];
  const float* gWout=(const float*)d_in[3];
  const float* fW1  =(const float*)d_in[4];
  const float* fb1  =(const float*)d_in[5];
  const float* fWout=(const float*)d_in[6];
  const float* fbout=(const float*)d_in[7];
  float* out=(float*)d_out;

  u16t* gidx16=(u16t*)d_ws;          // 1 MB
  float* xout = out + (size_t)B_*M_*3;

  fps_kernel    <<<dim3(B_),        dim3(256), 0, stream>>>(xyz, out);
  knn_kernel    <<<dim3((B_*M_)/4), dim3(256), 0, stream>>>(xyz, out, gidx16);
  geofeat_kernel<<<dim3(768),       dim3(256), 0, stream>>>(
      xyz, out, gidx16, gW1, gWout, feats, fW1, fb1, fWout, fbout, xout);
}